// Round 1
// baseline (1908.642 us; speedup 1.0000x reference)
//
#include <hip/hip_runtime.h>
#include <hip/hip_fp16.h>
#include <stdint.h>

// DIEN (GRU -> DIN attention -> AUGRU) on MI355X.
// Round 0: correctness-first f16-dot2 vector implementation.
//   K0 prep: weights f32->f16, attention fold (A1/B1/C1), W2/Wf
//   K0b: qdot[b,o] = b1 + A1 . q[b]   (t-invariant part of attention MLP)
//   K1 scan<GRU>:  per 32-step chunk: gi GEMM (Wih in LDS) -> L2 scratch, then
//                  recurrence with Whh rows held in 192 VGPRs, h broadcast via LDS.
//   K2 attention MLP (folded), K3 masked softmax, K4 scan<AUGRU> -> d_out.
// ws usage ~80.2 MB.

#define B_   1024
#define T_   200
#define H_   128
#define G3_  384
#define CH_  32
#define SCAN_BLOCKS 256
#define TS_  64

typedef _Float16 f16;
typedef _Float16 h2 __attribute__((ext_vector_type(2)));
typedef _Float16 h8 __attribute__((ext_vector_type(8)));

union H8U { h8 v; h2 p[4]; };

#define USE_FDOT2 1   // flip to 0 if v_dot2_f32_f16 unavailable on gfx950

__device__ __forceinline__ float dot2a(h2 a, h2 b, float acc) {
#if USE_FDOT2
  return __builtin_amdgcn_fdot2(a, b, acc, false);
#else
  return fmaf((float)a[1], (float)b[1], fmaf((float)a[0], (float)b[0], acc));
#endif
}

__device__ __forceinline__ float sig_(float x)  { return 1.f / (1.f + __expf(-x)); }
__device__ __forceinline__ float tanh_(float x) { return 1.f - 2.f / (__expf(2.f * x) + 1.f); }

// ---------------------------------------------------------------- prep
__global__ void prep_kernel(
    const float* __restrict__ Wih_e, const float* __restrict__ Whh_e,
    const float* __restrict__ Wih_a, const float* __restrict__ Whh_a,
    const float* __restrict__ W1, const float* __restrict__ W2,
    const float* __restrict__ Wf,
    f16* __restrict__ wih_e_h, f16* __restrict__ whh_e_h,
    f16* __restrict__ wih_a_h, f16* __restrict__ whh_a_h,
    f16* __restrict__ B1h, f16* __restrict__ C1h, float* __restrict__ A1f,
    f16* __restrict__ W2h, f16* __restrict__ Wfh)
{
  int i = blockIdx.x * 256 + threadIdx.x;
  const int NW = G3_ * H_;
  if (i < NW) { wih_e_h[i] = (f16)Wih_e[i]; return; }  i -= NW;
  if (i < NW) { whh_e_h[i] = (f16)Whh_e[i]; return; }  i -= NW;
  if (i < NW) { wih_a_h[i] = (f16)Wih_a[i]; return; }  i -= NW;
  if (i < NW) { whh_a_h[i] = (f16)Whh_a[i]; return; }  i -= NW;
  const int NB = 80 * 128;
  if (i < NB) { int o = i >> 7, jj = i & 127;
    B1h[i] = (f16)(W1[o * 512 + 128 + jj] - W1[o * 512 + 256 + jj]); return; }  i -= NB;
  if (i < NB) { int o = i >> 7, jj = i & 127;
    C1h[i] = (f16)(W1[o * 512 + 384 + jj]); return; }  i -= NB;
  if (i < NB) { int o = i >> 7, jj = i & 127;
    A1f[i] = W1[o * 512 + jj] + W1[o * 512 + 256 + jj]; return; }  i -= NB;
  if (i < 40 * 80) { W2h[i] = (f16)W2[i]; return; }  i -= 40 * 80;
  if (i < 40) { Wfh[i] = (f16)Wf[i]; return; }
}

// qdot[b][o] = b1[o] + sum_j A1[o][j] * q[b][j]    (fp32)
__global__ void qdot_kernel(const float* __restrict__ query, const float* __restrict__ A1f,
                            const float* __restrict__ b1, float* __restrict__ qdotp)
{
  const int b = blockIdx.x, o = threadIdx.x;
  if (o >= 80) return;
  float acc = b1[o];
  const float* qa = query + b * H_;
  const float* aa = A1f + o * H_;
  for (int jj = 0; jj < H_; ++jj) acc = fmaf(aa[jj], qa[jj], acc);
  qdotp[b * 80 + o] = acc;
}

// ---------------------------------------------------------------- scans
template <int AUGRU>
__global__ __launch_bounds__(256, 1) void scan_kernel(
    const float* __restrict__ keys_f32,   // GRU x source (f32) or null
    const f16*  __restrict__ x_f16,       // AUGRU x source (f16 interests) or null
    const int*  __restrict__ lens,
    const f16*  __restrict__ wih,         // [384][128] f16
    const f16*  __restrict__ whh,         // [384][128] f16
    const float* __restrict__ bih,
    const float* __restrict__ bhh,
    const float* __restrict__ scores,     // AUGRU only
    f16*  __restrict__ interests_out,     // GRU only
    float* __restrict__ hout,             // AUGRU only
    f16*  __restrict__ gi_all)            // [blocks][CH*4*384] scratch
{
  __shared__ alignas(16) f16 wlds[G3_ * H_];        // Wih, resident whole kernel
  __shared__ alignas(16) f16 xlds[CH_ * 4 * H_];    // x chunk
  __shared__ alignas(16) f16 hbuf[2][4 * H_];       // double-buffered h (f16 operand)
  __shared__ float bihs[G3_];
  __shared__ int lens_s[4];

  const int tid = threadIdx.x;
  const int b0 = blockIdx.x * 4;
  f16* gi_ws = gi_all + (size_t)blockIdx.x * (CH_ * 4 * G3_);

  if (tid < 4) lens_s[tid] = lens[b0 + tid];
  for (int i = tid; i < G3_; i += 256) bihs[i] = bih[i];
  for (int i = tid; i < 2 * 4 * H_; i += 256) ((f16*)hbuf)[i] = (f16)0.f;
  { // Wih -> LDS (once)
    const uint4* src = (const uint4*)wih;
    uint4* dst = (uint4*)wlds;
    for (int idx = tid; idx < G3_ * H_ / 8; idx += 256) dst[idx] = src[idx];
  }

  const int j  = tid & 127;   // h column owned
  const int bp = tid >> 7;    // batches bp, bp+2
  const float bhr = bhh[j], bhz = bhh[j + 128], bhn = bhh[j + 256];
  const int mg = tid >> 4;    // phase-A m-group
  const int n0 = tid & 15;    // phase-A n-group

  // Whh rows j, j+128, j+256 -> 192 VGPRs (constant over all T)
  H8U wr_r[16], wr_z[16], wr_n[16];
#pragma unroll
  for (int c = 0; c < 16; ++c) {
    wr_r[c].v = *(const h8*)(whh + (size_t)(j)       * H_ + c * 8);
    wr_z[c].v = *(const h8*)(whh + (size_t)(j + 128) * H_ + c * 8);
    wr_n[c].v = *(const h8*)(whh + (size_t)(j + 256) * H_ + c * 8);
  }

  float hreg[2] = {0.f, 0.f};
  int p = 0;
  __syncthreads();

  for (int t0 = 0; t0 < T_; t0 += CH_) {
    const int S = (T_ - t0 < CH_) ? (T_ - t0) : CH_;
    // ---- A1: stage x chunk into xlds (f16), layout [t'][b][j] ----
    if (AUGRU) {
      const int NV = S * 4 * 16;                    // uint4 units
      for (int idx = tid; idx < NV; idx += 256) {
        int b = idx / (S * 16);
        int rem = idx - b * (S * 16);
        int tp = rem >> 4, c = rem & 15;
        const uint4* src = (const uint4*)(x_f16 + ((size_t)(b0 + b) * T_ + (t0 + tp)) * H_);
        ((uint4*)xlds)[(tp * 4 + b) * 16 + c] = src[c];
      }
    } else {
      const int NV = S * 4 * 32;                    // float4 units
      for (int idx = tid; idx < NV; idx += 256) {
        int b = idx / (S * 32);
        int rem = idx - b * (S * 32);
        int tp = rem >> 5, c = rem & 31;
        const float4* src = (const float4*)(keys_f32 + ((size_t)(b0 + b) * T_ + (t0 + tp)) * H_);
        float4 v = src[c];
        f16* dst = &xlds[(tp * 4 + b) * H_ + c * 4];
        dst[0] = (f16)v.x; dst[1] = (f16)v.y; dst[2] = (f16)v.z; dst[3] = (f16)v.w;
      }
    }
    __syncthreads();
    // ---- A3: gi = x @ Wih^T + bih  (reg-tiled 8x8, rotated k-chunks) ----
    for (int ngrp = 0; ngrp < 3; ++ngrp) {
      float acc[8][8];
#pragma unroll
      for (int a = 0; a < 8; ++a)
#pragma unroll
        for (int c = 0; c < 8; ++c) acc[a][c] = 0.f;
      for (int kc = 0; kc < 16; ++kc) {
        const int kcp = (kc + n0) & 15;
        H8U xr[8], wr[8];
#pragma unroll
        for (int mi = 0; mi < 8; ++mi)
          xr[mi].v = *(const h8*)&xlds[(mg * 8 + mi) * H_ + kcp * 8];
#pragma unroll
        for (int ni = 0; ni < 8; ++ni)
          wr[ni].v = *(const h8*)&wlds[(n0 * 24 + ngrp * 8 + ni) * H_ + kcp * 8];
#pragma unroll
        for (int mi = 0; mi < 8; ++mi)
#pragma unroll
          for (int ni = 0; ni < 8; ++ni)
#pragma unroll
            for (int q = 0; q < 4; ++q)
              acc[mi][ni] = dot2a(xr[mi].p[q], wr[ni].p[q], acc[mi][ni]);
      }
#pragma unroll
      for (int mi = 0; mi < 8; ++mi) {
        const int pr = mg * 8 + mi;
        if (pr < S * 4) {
          H8U o8;
#pragma unroll
          for (int ni = 0; ni < 8; ++ni) {
            const int g = n0 * 24 + ngrp * 8 + ni;
            o8.p[ni >> 1][ni & 1] = (f16)(acc[mi][ni] + bihs[g]);
          }
          *(h8*)&gi_ws[(size_t)pr * G3_ + n0 * 24 + ngrp * 8] = o8.v;
        }
      }
    }
    __syncthreads();   // gi visible to block
    // ---- B: recurrence over chunk ----
    for (int tp = 0; tp < S; ++tp) {
      const int t = t0 + tp;
      float hr[2] = {0.f, 0.f}, hz[2] = {0.f, 0.f}, hn[2] = {0.f, 0.f};
#pragma unroll
      for (int kc = 0; kc < 16; ++kc) {
        H8U hv0, hv1;   // wave-uniform broadcast reads
        hv0.v = *(const h8*)&hbuf[p][(bp)     * H_ + kc * 8];
        hv1.v = *(const h8*)&hbuf[p][(bp + 2) * H_ + kc * 8];
#pragma unroll
        for (int q = 0; q < 4; ++q) {
          hr[0] = dot2a(wr_r[kc].p[q], hv0.p[q], hr[0]);
          hz[0] = dot2a(wr_z[kc].p[q], hv0.p[q], hz[0]);
          hn[0] = dot2a(wr_n[kc].p[q], hv0.p[q], hn[0]);
          hr[1] = dot2a(wr_r[kc].p[q], hv1.p[q], hr[1]);
          hz[1] = dot2a(wr_z[kc].p[q], hv1.p[q], hz[1]);
          hn[1] = dot2a(wr_n[kc].p[q], hv1.p[q], hn[1]);
        }
      }
#pragma unroll
      for (int bb = 0; bb < 2; ++bb) {
        const int b = bp + bb * 2;
        const int gb = b0 + b;
        const f16* gi = &gi_ws[(size_t)(tp * 4 + b) * G3_];
        const float gr  = (float)gi[j]       + hr[bb] + bhr;
        const float gz  = (float)gi[j + 128] + hz[bb] + bhz;
        const float gin = (float)gi[j + 256];
        const float r = sig_(gr);
        const float nn = tanh_(gin + r * (hn[bb] + bhn));
        float hnew;
        if (AUGRU) {
          const float a = scores[(size_t)gb * T_ + t];
          const float u = sig_(gz) * a;
          hnew = (1.f - u) * hreg[bb] + u * nn;          // AUGRU: u gates NEW state
        } else {
          const float z = sig_(gz);
          hnew = (1.f - z) * nn + z * hreg[bb];          // torch GRU convention
        }
        if (t < lens_s[b]) hreg[bb] = hnew;              // freeze past length
        hbuf[p ^ 1][b * H_ + j] = (f16)hreg[bb];
        if (!AUGRU) interests_out[((size_t)gb * T_ + t) * H_ + j] = (f16)hreg[bb];
      }
      __syncthreads();
      p ^= 1;
    }
  }
  if (AUGRU) {
    hout[(size_t)(b0 + bp) * H_ + j]     = hreg[0];
    hout[(size_t)(b0 + bp + 2) * H_ + j] = hreg[1];
  }
}

// ---------------------------------------------------------------- attention
__global__ __launch_bounds__(320, 2) void attn_kernel(
    const float* __restrict__ query,
    const f16* __restrict__ interests,
    const f16* __restrict__ B1h, const f16* __restrict__ C1h,
    const f16* __restrict__ W2h, const f16* __restrict__ Wfh,
    const float* __restrict__ qdotp, const float* __restrict__ b2,
    const float* __restrict__ bfp,
    float* __restrict__ logits)
{
  __shared__ alignas(16) f16 B1s[80 * 128];
  __shared__ alignas(16) f16 C1s[80 * 128];
  __shared__ alignas(16) f16 kt[TS_ * 128];
  __shared__ alignas(16) f16 qh[128];
  __shared__ alignas(16) f16 W2s[40 * 80];
  __shared__ alignas(16) f16 Wfs[48];
  __shared__ alignas(16) f16 h1t[TS_ * 80];
  __shared__ alignas(16) f16 h2t[TS_ * 40];
  __shared__ float qd[80];
  __shared__ float b2s[40];

  const int tid = threadIdx.x;
  const int b = blockIdx.x >> 2;
  const int t0 = (blockIdx.x & 3) * TS_;

  for (int i = tid; i < 80 * 128 / 8; i += 320) ((uint4*)B1s)[i] = ((const uint4*)B1h)[i];
  for (int i = tid; i < 80 * 128 / 8; i += 320) ((uint4*)C1s)[i] = ((const uint4*)C1h)[i];
  for (int i = tid; i < 40 * 80 / 8; i += 320) ((uint4*)W2s)[i] = ((const uint4*)W2h)[i];
  if (tid < 40) { Wfs[tid] = Wfh[tid]; b2s[tid] = b2[tid]; }
  if (tid < 80) qd[tid] = qdotp[b * 80 + tid];
  if (tid < 128) qh[tid] = (f16)query[b * 128 + tid];
  for (int i = tid; i < TS_ * 16; i += 320) {
    const int tt = i >> 4, c = i & 15;
    const int t = t0 + tt;
    uint4 v = make_uint4(0u, 0u, 0u, 0u);
    if (t < T_) v = ((const uint4*)(interests + ((size_t)b * T_ + t) * H_))[c];
    ((uint4*)kt)[i] = v;
  }
  __syncthreads();

  { // phase 1: h1[t][o] = sigmoid(qdot[o] + B1[o].k + C1[o].(q*k))
    const int og = tid % 20, tg = tid / 20;     // o = og*4+oi, t = tg*4+ti
    float acc[4][4];
#pragma unroll
    for (int a = 0; a < 4; ++a)
#pragma unroll
      for (int c = 0; c < 4; ++c) acc[a][c] = 0.f;
    for (int kc = 0; kc < 16; ++kc) {
      const int kcp = (kc + og) & 15;
      H8U qv; qv.v = *(const h8*)&qh[kcp * 8];
      H8U bv[4], cv[4], kv[4];
#pragma unroll
      for (int oi = 0; oi < 4; ++oi) {
        bv[oi].v = *(const h8*)&B1s[(og * 4 + oi) * 128 + kcp * 8];
        cv[oi].v = *(const h8*)&C1s[(og * 4 + oi) * 128 + kcp * 8];
      }
#pragma unroll
      for (int ti = 0; ti < 4; ++ti) kv[ti].v = *(const h8*)&kt[(tg * 4 + ti) * 128 + kcp * 8];
#pragma unroll
      for (int ti = 0; ti < 4; ++ti) {
        H8U mv;
#pragma unroll
        for (int q = 0; q < 4; ++q) mv.p[q] = qv.p[q] * kv[ti].p[q];
#pragma unroll
        for (int oi = 0; oi < 4; ++oi)
#pragma unroll
          for (int q = 0; q < 4; ++q) {
            acc[ti][oi] = dot2a(bv[oi].p[q], kv[ti].p[q], acc[ti][oi]);
            acc[ti][oi] = dot2a(cv[oi].p[q], mv.p[q],     acc[ti][oi]);
          }
      }
    }
#pragma unroll
    for (int ti = 0; ti < 4; ++ti)
#pragma unroll
      for (int oi = 0; oi < 4; ++oi) {
        const int o = og * 4 + oi, t = tg * 4 + ti;
        h1t[t * 80 + o] = (f16)sig_(acc[ti][oi] + qd[o]);
      }
  }
  __syncthreads();
  { // phase 2: h2 = sigmoid(h1 @ W2^T + b2)
    const int o2g = tid % 10, tg = tid / 10;    // o = o2g*4+oi, t = tg*2+ti
    float acc[2][4];
#pragma unroll
    for (int a = 0; a < 2; ++a)
#pragma unroll
      for (int c = 0; c < 4; ++c) acc[a][c] = 0.f;
    for (int kc = 0; kc < 10; ++kc) {
      const int kcp = (kc + o2g) % 10;
      H8U wv[4], hv[2];
#pragma unroll
      for (int oi = 0; oi < 4; ++oi) wv[oi].v = *(const h8*)&W2s[(o2g * 4 + oi) * 80 + kcp * 8];
#pragma unroll
      for (int ti = 0; ti < 2; ++ti) hv[ti].v = *(const h8*)&h1t[(tg * 2 + ti) * 80 + kcp * 8];
#pragma unroll
      for (int ti = 0; ti < 2; ++ti)
#pragma unroll
        for (int oi = 0; oi < 4; ++oi)
#pragma unroll
          for (int q = 0; q < 4; ++q) acc[ti][oi] = dot2a(wv[oi].p[q], hv[ti].p[q], acc[ti][oi]);
    }
#pragma unroll
    for (int ti = 0; ti < 2; ++ti)
#pragma unroll
      for (int oi = 0; oi < 4; ++oi) {
        const int o = o2g * 4 + oi, t = tg * 2 + ti;
        h2t[t * 40 + o] = (f16)sig_(acc[ti][oi] + b2s[o]);
      }
  }
  __syncthreads();
  // phase 3: logit = (h2 . Wf + bf) / sqrt(128)
  if (tid < TS_) {
    const int t = t0 + tid;
    if (t < T_) {
      float acc = 0.f;
      for (int kc = 0; kc < 5; ++kc) {
        H8U wv, hv;
        wv.v = *(const h8*)&Wfs[kc * 8];
        hv.v = *(const h8*)&h2t[tid * 40 + kc * 8];
#pragma unroll
        for (int q = 0; q < 4; ++q) acc = dot2a(wv.p[q], hv.p[q], acc);
      }
      logits[(size_t)b * T_ + t] = (acc + bfp[0]) * 0.088388347648318447f;
    }
  }
}

// ---------------------------------------------------------------- softmax
__global__ __launch_bounds__(256, 1) void softmax_kernel(
    const float* __restrict__ logits, const int* __restrict__ lens,
    float* __restrict__ scores)
{
  __shared__ float red[256];
  const int b = blockIdx.x, tid = threadIdx.x;
  const int len = lens[b];
  float v = -1e30f;
  if (tid < T_ && tid < len) v = logits[(size_t)b * T_ + tid];
  red[tid] = v; __syncthreads();
  for (int s = 128; s > 0; s >>= 1) {
    if (tid < s) red[tid] = fmaxf(red[tid], red[tid + s]);
    __syncthreads();
  }
  const float mx = red[0]; __syncthreads();
  float e = 0.f;
  if (tid < T_ && tid < len) e = __expf(v - mx);
  red[tid] = e; __syncthreads();
  for (int s = 128; s > 0; s >>= 1) {
    if (tid < s) red[tid] += red[tid + s];
    __syncthreads();
  }
  const float inv = 1.f / red[0];
  if (tid < T_) scores[(size_t)b * T_ + tid] = e * inv;
}

// ---------------------------------------------------------------- launcher
extern "C" void kernel_launch(void* const* d_in, const int* in_sizes, int n_in,
                              void* d_out, int out_size, void* d_ws, size_t ws_size,
                              hipStream_t stream)
{
  (void)in_sizes; (void)n_in; (void)out_size; (void)ws_size;
  const float* query = (const float*)d_in[0];
  const float* keys  = (const float*)d_in[1];
  const int*   lens  = (const int*)d_in[2];
  const float* Wih_e = (const float*)d_in[3];
  const float* Whh_e = (const float*)d_in[4];
  const float* bih_e = (const float*)d_in[5];
  const float* bhh_e = (const float*)d_in[6];
  const float* Wih_a = (const float*)d_in[7];
  const float* Whh_a = (const float*)d_in[8];
  const float* bih_a = (const float*)d_in[9];
  const float* bhh_a = (const float*)d_in[10];
  const float* W1 = (const float*)d_in[11];
  const float* b1 = (const float*)d_in[12];
  const float* W2 = (const float*)d_in[13];
  const float* b2 = (const float*)d_in[14];
  const float* Wf = (const float*)d_in[15];
  const float* bf = (const float*)d_in[16];

  char* w = (char*)d_ws;
  size_t off = 0;
  auto take = [&](size_t bytes) { char* p = w + off; off += (bytes + 255) & ~(size_t)255; return p; };
  f16*   interests = (f16*)take((size_t)B_ * T_ * H_ * 2);
  float* logits    = (float*)take((size_t)B_ * T_ * 4);
  float* scores    = (float*)take((size_t)B_ * T_ * 4);
  f16*   wih_e_h = (f16*)take(G3_ * H_ * 2);
  f16*   whh_e_h = (f16*)take(G3_ * H_ * 2);
  f16*   wih_a_h = (f16*)take(G3_ * H_ * 2);
  f16*   whh_a_h = (f16*)take(G3_ * H_ * 2);
  f16*   B1h = (f16*)take(80 * 128 * 2);
  f16*   C1h = (f16*)take(80 * 128 * 2);
  float* A1f = (float*)take(80 * 128 * 4);
  f16*   W2h = (f16*)take(40 * 80 * 2);
  f16*   Wfh = (f16*)take(64 * 2);
  float* qdotp = (float*)take((size_t)B_ * 80 * 4);
  f16*   gi_ws = (f16*)take((size_t)SCAN_BLOCKS * CH_ * 4 * G3_ * 2);

  const int prep_tasks = 4 * G3_ * H_ + 3 * 80 * 128 + 40 * 80 + 40;
  prep_kernel<<<(prep_tasks + 255) / 256, 256, 0, stream>>>(
      Wih_e, Whh_e, Wih_a, Whh_a, W1, W2, Wf,
      wih_e_h, whh_e_h, wih_a_h, whh_a_h, B1h, C1h, A1f, W2h, Wfh);
  qdot_kernel<<<B_, 128, 0, stream>>>(query, A1f, b1, qdotp);
  scan_kernel<0><<<SCAN_BLOCKS, 256, 0, stream>>>(
      keys, (const f16*)nullptr, lens, wih_e_h, whh_e_h, bih_e, bhh_e,
      (const float*)nullptr, interests, (float*)nullptr, gi_ws);
  attn_kernel<<<B_ * 4, 320, 0, stream>>>(
      query, interests, B1h, C1h, W2h, Wfh, qdotp, b2, bf, logits);
  softmax_kernel<<<B_, 256, 0, stream>>>(logits, lens, scores);
  scan_kernel<1><<<SCAN_BLOCKS, 256, 0, stream>>>(
      (const float*)nullptr, interests, lens, wih_a_h, whh_a_h, bih_a, bhh_a,
      scores, (f16*)nullptr, (float*)d_out, gi_ws);
}

// Round 3
// 1276.639 us; speedup vs baseline: 1.4951x; 1.4951x over previous
//
#include <hip/hip_runtime.h>
#include <hip/hip_fp16.h>
#include <stdint.h>

// DIEN (GRU -> DIN attention -> AUGRU) on MI355X.
// R2: fix data race in srec_kernel (lens_s read before first barrier ->
// nondeterministic freeze length -> graph-replay tripwire). lens now read
// directly from global per thread. Structure otherwise identical to R1:
//   gi = x@Wih^T + bih hoisted into standalone f16-dot2 GEMM (2 blocks/CU);
//   scans recurrence-only (Whh in 192 VGPRs, h broadcast via LDS, 2 blocks/CU).

#define B_   1024
#define T_   200
#define H_   128
#define G3_  384
#define CH_  32
#define SCAN_BLOCKS 256
#define TS_  64

typedef _Float16 f16;
typedef _Float16 h2 __attribute__((ext_vector_type(2)));
typedef _Float16 h8 __attribute__((ext_vector_type(8)));

union H8U { h8 v; h2 p[4]; };

#define USE_FDOT2 1

__device__ __forceinline__ float dot2a(h2 a, h2 b, float acc) {
#if USE_FDOT2
  return __builtin_amdgcn_fdot2(a, b, acc, false);
#else
  return fmaf((float)a[1], (float)b[1], fmaf((float)a[0], (float)b[0], acc));
#endif
}

__device__ __forceinline__ float sig_(float x)  { return 1.f / (1.f + __expf(-x)); }
__device__ __forceinline__ float tanh_(float x) { return 1.f - 2.f / (__expf(2.f * x) + 1.f); }

// ---------------------------------------------------------------- prep
__global__ void prep_kernel(
    const float* __restrict__ Wih_e, const float* __restrict__ Whh_e,
    const float* __restrict__ Wih_a, const float* __restrict__ Whh_a,
    const float* __restrict__ W1, const float* __restrict__ W2,
    const float* __restrict__ Wf,
    f16* __restrict__ wih_e_h, f16* __restrict__ whh_e_h,
    f16* __restrict__ wih_a_h, f16* __restrict__ whh_a_h,
    f16* __restrict__ B1h, f16* __restrict__ C1h, float* __restrict__ A1f,
    f16* __restrict__ W2h, f16* __restrict__ Wfh)
{
  int i = blockIdx.x * 256 + threadIdx.x;
  const int NW = G3_ * H_;
  if (i < NW) { wih_e_h[i] = (f16)Wih_e[i]; return; }  i -= NW;
  if (i < NW) { whh_e_h[i] = (f16)Whh_e[i]; return; }  i -= NW;
  if (i < NW) { wih_a_h[i] = (f16)Wih_a[i]; return; }  i -= NW;
  if (i < NW) { whh_a_h[i] = (f16)Whh_a[i]; return; }  i -= NW;
  const int NB = 80 * 128;
  if (i < NB) { int o = i >> 7, jj = i & 127;
    B1h[i] = (f16)(W1[o * 512 + 128 + jj] - W1[o * 512 + 256 + jj]); return; }  i -= NB;
  if (i < NB) { int o = i >> 7, jj = i & 127;
    C1h[i] = (f16)(W1[o * 512 + 384 + jj]); return; }  i -= NB;
  if (i < NB) { int o = i >> 7, jj = i & 127;
    A1f[i] = W1[o * 512 + jj] + W1[o * 512 + 256 + jj]; return; }  i -= NB;
  if (i < 40 * 80) { W2h[i] = (f16)W2[i]; return; }  i -= 40 * 80;
  if (i < 40) { Wfh[i] = (f16)Wf[i]; return; }
}

// qdot[b][o] = b1[o] + sum_j A1[o][j] * q[b][j]
__global__ void qdot_kernel(const float* __restrict__ query, const float* __restrict__ A1f,
                            const float* __restrict__ b1, float* __restrict__ qdotp)
{
  const int b = blockIdx.x, o = threadIdx.x;
  if (o >= 80) return;
  float acc = b1[o];
  const float* qa = query + b * H_;
  const float* aa = A1f + o * H_;
  for (int jj = 0; jj < H_; ++jj) acc = fmaf(aa[jj], qa[jj], acc);
  qdotp[b * 80 + o] = acc;
}

// ---------------------------------------------------------------- gi GEMM
// gi[m][c] = bih[c] + sum_k x[m][k] * wih[c][k]   for m in [0, B*T)
// block: 256 thr, 128 rows x 192 cols (half = blockIdx&1). 8x12 reg tile.
// LDS 80KB -> 2 blocks/CU.
template <int XF32>
__global__ __launch_bounds__(256, 2) void gi_gemm_kernel(
    const float* __restrict__ xf32,   // XF32: [M,128] f32
    const f16*  __restrict__ xh,      // else: [M,128] f16
    const f16*  __restrict__ wih,     // [384][128]
    const float* __restrict__ bih,
    f16* __restrict__ gi)             // [M,384]
{
  __shared__ alignas(16) f16 xs[128 * H_];   // 32KB
  __shared__ alignas(16) f16 ws[192 * H_];   // 48KB
  const int tid = threadIdx.x;
  const int m0   = (blockIdx.x >> 1) * 128;
  const int half = blockIdx.x & 1;

  if (XF32) {
    for (int i = tid; i < 128 * 32; i += 256) {
      const int r = i >> 5, c = i & 31;
      float4 v = ((const float4*)(xf32 + (size_t)(m0 + r) * H_))[c];
      f16* dst = &xs[r * H_ + c * 4];
      dst[0] = (f16)v.x; dst[1] = (f16)v.y; dst[2] = (f16)v.z; dst[3] = (f16)v.w;
    }
  } else {
    const uint4* src = (const uint4*)(xh + (size_t)m0 * H_);
    for (int i = tid; i < 128 * 16; i += 256) ((uint4*)xs)[i] = src[i];
  }
  {
    const uint4* wsrc = (const uint4*)(wih + (size_t)half * 192 * H_);
    for (int i = tid; i < 192 * 16; i += 256) ((uint4*)ws)[i] = wsrc[i];
  }
  const int mg = tid >> 4;   // 0..15 -> rows mg*8..mg*8+7
  const int n0 = tid & 15;   // 0..15 -> cols n0*12..n0*12+11 (within half)
  const int cb = half * 192 + n0 * 12;
  float bias[12];
#pragma unroll
  for (int ci = 0; ci < 12; ++ci) bias[ci] = bih[cb + ci];
  __syncthreads();

  float acc[8][12];
#pragma unroll
  for (int a = 0; a < 8; ++a)
#pragma unroll
    for (int c = 0; c < 12; ++c) acc[a][c] = 0.f;

  for (int kc = 0; kc < 16; ++kc) {
    const int kcp = (kc + n0) & 15;
    H8U xr[8], wr[12];
#pragma unroll
    for (int mi = 0; mi < 8; ++mi)
      xr[mi].v = *(const h8*)&xs[(mg * 8 + mi) * H_ + kcp * 8];
#pragma unroll
    for (int ci = 0; ci < 12; ++ci)
      wr[ci].v = *(const h8*)&ws[(n0 * 12 + ci) * H_ + kcp * 8];
#pragma unroll
    for (int mi = 0; mi < 8; ++mi)
#pragma unroll
      for (int ci = 0; ci < 12; ++ci)
#pragma unroll
        for (int q = 0; q < 4; ++q)
          acc[mi][ci] = dot2a(xr[mi].p[q], wr[ci].p[q], acc[mi][ci]);
  }

#pragma unroll
  for (int mi = 0; mi < 8; ++mi) {
    const size_t row = (size_t)(m0 + mg * 8 + mi);
    f16 o12[12];
#pragma unroll
    for (int ci = 0; ci < 12; ++ci) o12[ci] = (f16)(acc[mi][ci] + bias[ci]);
    f16* dst = gi + row * G3_ + cb;
#pragma unroll
    for (int s = 0; s < 3; ++s)
      ((uint2*)dst)[s] = *(const uint2*)&o12[s * 4];
  }
}

// ---------------------------------------------------------------- recurrence
// 2 batches/block, 512 blocks -> 2 blocks/CU. gi precomputed (f16, L3).
template <int AUGRU>
__global__ __launch_bounds__(256, 2) void srec_kernel(
    const f16*  __restrict__ gi_all,  // [B*T,384]
    const int*  __restrict__ lens,
    const f16*  __restrict__ whh,     // [384][128]
    const float* __restrict__ bhh,
    const float* __restrict__ scores,   // AUGRU only
    f16*  __restrict__ interests_out,   // GRU only
    float* __restrict__ hout)           // AUGRU only
{
  __shared__ f16 hbuf[2][2 * H_];

  const int tid = threadIdx.x;
  const int j  = tid & 127;
  const int bp = tid >> 7;
  const int b0 = blockIdx.x * 2;
  const int gb = b0 + bp;

  hbuf[0][tid] = (f16)0.f;
  // R2 FIX: read lens directly from global per-thread (the R1 LDS staging of
  // lens was read before the first __syncthreads -> data race -> the
  // graph-replay tripwire). Direct global read has no ordering hazard.
  const int mylen = lens[gb];

  const float bhr = bhh[j], bhz = bhh[j + 128], bhn = bhh[j + 256];

  H8U wr_r[16], wr_z[16], wr_n[16];   // 192 VGPRs, constant over T
#pragma unroll
  for (int c = 0; c < 16; ++c) {
    wr_r[c].v = *(const h8*)(whh + (size_t)(j)       * H_ + c * 8);
    wr_z[c].v = *(const h8*)(whh + (size_t)(j + 128) * H_ + c * 8);
    wr_n[c].v = *(const h8*)(whh + (size_t)(j + 256) * H_ + c * 8);
  }

  const f16* gibase = gi_all + (size_t)gb * T_ * G3_;
  float h = 0.f;
  int p = 0;

  // prefetch t=0
  f16 a0 = gibase[j], a1 = gibase[j + 128], a2 = gibase[j + 256];
  float sc = AUGRU ? scores[(size_t)gb * T_] : 0.f;
  __syncthreads();

  for (int t = 0; t < T_; ++t) {
    // issue prefetch for t+1 (independent of h)
    const int tn = (t + 1 < T_) ? (t + 1) : t;
    const f16* gn = gibase + (size_t)tn * G3_;
    const f16 n0_ = gn[j], n1_ = gn[j + 128], n2_ = gn[j + 256];
    const float scn = AUGRU ? scores[(size_t)gb * T_ + tn] : 0.f;

    float dr = 0.f, dz = 0.f, dn = 0.f;
#pragma unroll
    for (int kc = 0; kc < 16; ++kc) {
      H8U hv;   // wave-uniform broadcast read
      hv.v = *(const h8*)&hbuf[p][bp * H_ + kc * 8];
#pragma unroll
      for (int q = 0; q < 4; ++q) {
        dr = dot2a(wr_r[kc].p[q], hv.p[q], dr);
        dz = dot2a(wr_z[kc].p[q], hv.p[q], dz);
        dn = dot2a(wr_n[kc].p[q], hv.p[q], dn);
      }
    }
    const float gr  = (float)a0 + dr + bhr;
    const float gz  = (float)a1 + dz + bhz;
    const float gin = (float)a2;
    const float r  = sig_(gr);
    const float nn = tanh_(gin + r * (dn + bhn));
    float hnew;
    if (AUGRU) {
      const float u = sig_(gz) * sc;
      hnew = (1.f - u) * h + u * nn;        // AUGRU: u gates NEW state
    } else {
      const float z = sig_(gz);
      hnew = (1.f - z) * nn + z * h;        // torch GRU convention
    }
    if (t < mylen) h = hnew;                // freeze past length
    hbuf[p ^ 1][bp * H_ + j] = (f16)h;
    if (!AUGRU) interests_out[((size_t)gb * T_ + t) * H_ + j] = (f16)h;
    a0 = n0_; a1 = n1_; a2 = n2_; sc = scn;
    __syncthreads();
    p ^= 1;
  }
  if (AUGRU) hout[(size_t)gb * H_ + j] = h;
}

// ================================================================ fallback
// (round-0 monolithic scan, used only if ws_size can't hold the gi buffer)
template <int AUGRU>
__global__ __launch_bounds__(256, 1) void scan_kernel(
    const float* __restrict__ keys_f32,
    const f16*  __restrict__ x_f16,
    const int*  __restrict__ lens,
    const f16*  __restrict__ wih,
    const f16*  __restrict__ whh,
    const float* __restrict__ bih,
    const float* __restrict__ bhh,
    const float* __restrict__ scores,
    f16*  __restrict__ interests_out,
    float* __restrict__ hout,
    f16*  __restrict__ gi_all)
{
  __shared__ alignas(16) f16 wlds[G3_ * H_];
  __shared__ alignas(16) f16 xlds[CH_ * 4 * H_];
  __shared__ alignas(16) f16 hbuf[2][4 * H_];
  __shared__ float bihs[G3_];

  const int tid = threadIdx.x;
  const int b0 = blockIdx.x * 4;
  f16* gi_ws = gi_all + (size_t)blockIdx.x * (CH_ * 4 * G3_);

  for (int i = tid; i < G3_; i += 256) bihs[i] = bih[i];
  for (int i = tid; i < 2 * 4 * H_; i += 256) ((f16*)hbuf)[i] = (f16)0.f;
  {
    const uint4* src = (const uint4*)wih;
    uint4* dst = (uint4*)wlds;
    for (int idx = tid; idx < G3_ * H_ / 8; idx += 256) dst[idx] = src[idx];
  }

  const int j  = tid & 127;
  const int bp = tid >> 7;
  const int len0 = lens[b0 + bp];       // direct global reads, no race
  const int len1 = lens[b0 + bp + 2];
  const float bhr = bhh[j], bhz = bhh[j + 128], bhn = bhh[j + 256];
  const int mg = tid >> 4;
  const int n0 = tid & 15;

  H8U wr_r[16], wr_z[16], wr_n[16];
#pragma unroll
  for (int c = 0; c < 16; ++c) {
    wr_r[c].v = *(const h8*)(whh + (size_t)(j)       * H_ + c * 8);
    wr_z[c].v = *(const h8*)(whh + (size_t)(j + 128) * H_ + c * 8);
    wr_n[c].v = *(const h8*)(whh + (size_t)(j + 256) * H_ + c * 8);
  }

  float hreg[2] = {0.f, 0.f};
  int p = 0;
  __syncthreads();

  for (int t0 = 0; t0 < T_; t0 += CH_) {
    const int S = (T_ - t0 < CH_) ? (T_ - t0) : CH_;
    if (AUGRU) {
      const int NV = S * 4 * 16;
      for (int idx = tid; idx < NV; idx += 256) {
        int b = idx / (S * 16);
        int rem = idx - b * (S * 16);
        int tp = rem >> 4, c = rem & 15;
        const uint4* src = (const uint4*)(x_f16 + ((size_t)(b0 + b) * T_ + (t0 + tp)) * H_);
        ((uint4*)xlds)[(tp * 4 + b) * 16 + c] = src[c];
      }
    } else {
      const int NV = S * 4 * 32;
      for (int idx = tid; idx < NV; idx += 256) {
        int b = idx / (S * 32);
        int rem = idx - b * (S * 32);
        int tp = rem >> 5, c = rem & 31;
        const float4* src = (const float4*)(keys_f32 + ((size_t)(b0 + b) * T_ + (t0 + tp)) * H_);
        float4 v = src[c];
        f16* dst = &xlds[(tp * 4 + b) * H_ + c * 4];
        dst[0] = (f16)v.x; dst[1] = (f16)v.y; dst[2] = (f16)v.z; dst[3] = (f16)v.w;
      }
    }
    __syncthreads();
    for (int ngrp = 0; ngrp < 3; ++ngrp) {
      float acc[8][8];
#pragma unroll
      for (int a = 0; a < 8; ++a)
#pragma unroll
        for (int c = 0; c < 8; ++c) acc[a][c] = 0.f;
      for (int kc = 0; kc < 16; ++kc) {
        const int kcp = (kc + n0) & 15;
        H8U xr[8], wr[8];
#pragma unroll
        for (int mi = 0; mi < 8; ++mi)
          xr[mi].v = *(const h8*)&xlds[(mg * 8 + mi) * H_ + kcp * 8];
#pragma unroll
        for (int ni = 0; ni < 8; ++ni)
          wr[ni].v = *(const h8*)&wlds[(n0 * 24 + ngrp * 8 + ni) * H_ + kcp * 8];
#pragma unroll
        for (int mi = 0; mi < 8; ++mi)
#pragma unroll
          for (int ni = 0; ni < 8; ++ni)
#pragma unroll
            for (int q = 0; q < 4; ++q)
              acc[mi][ni] = dot2a(xr[mi].p[q], wr[ni].p[q], acc[mi][ni]);
      }
#pragma unroll
      for (int mi = 0; mi < 8; ++mi) {
        const int pr = mg * 8 + mi;
        if (pr < S * 4) {
          H8U o8;
#pragma unroll
          for (int ni = 0; ni < 8; ++ni) {
            const int g = n0 * 24 + ngrp * 8 + ni;
            o8.p[ni >> 1][ni & 1] = (f16)(acc[mi][ni] + bihs[g]);
          }
          *(h8*)&gi_ws[(size_t)pr * G3_ + n0 * 24 + ngrp * 8] = o8.v;
        }
      }
    }
    __syncthreads();
    for (int tp = 0; tp < S; ++tp) {
      const int t = t0 + tp;
      float hr[2] = {0.f, 0.f}, hz[2] = {0.f, 0.f}, hn[2] = {0.f, 0.f};
#pragma unroll
      for (int kc = 0; kc < 16; ++kc) {
        H8U hv0, hv1;
        hv0.v = *(const h8*)&hbuf[p][(bp)     * H_ + kc * 8];
        hv1.v = *(const h8*)&hbuf[p][(bp + 2) * H_ + kc * 8];
#pragma unroll
        for (int q = 0; q < 4; ++q) {
          hr[0] = dot2a(wr_r[kc].p[q], hv0.p[q], hr[0]);
          hz[0] = dot2a(wr_z[kc].p[q], hv0.p[q], hz[0]);
          hn[0] = dot2a(wr_n[kc].p[q], hv0.p[q], hn[0]);
          hr[1] = dot2a(wr_r[kc].p[q], hv1.p[q], hr[1]);
          hz[1] = dot2a(wr_z[kc].p[q], hv1.p[q], hz[1]);
          hn[1] = dot2a(wr_n[kc].p[q], hv1.p[q], hn[1]);
        }
      }
#pragma unroll
      for (int bb = 0; bb < 2; ++bb) {
        const int b = bp + bb * 2;
        const int gb = b0 + b;
        const f16* gi = &gi_ws[(size_t)(tp * 4 + b) * G3_];
        const float gr  = (float)gi[j]       + hr[bb] + bhr;
        const float gz  = (float)gi[j + 128] + hz[bb] + bhz;
        const float gin = (float)gi[j + 256];
        const float r = sig_(gr);
        const float nn = tanh_(gin + r * (hn[bb] + bhn));
        float hnew;
        if (AUGRU) {
          const float a = scores[(size_t)gb * T_ + t];
          const float u = sig_(gz) * a;
          hnew = (1.f - u) * hreg[bb] + u * nn;
        } else {
          const float z = sig_(gz);
          hnew = (1.f - z) * nn + z * hreg[bb];
        }
        const int mylen = bb ? len1 : len0;
        if (t < mylen) hreg[bb] = hnew;
        hbuf[p ^ 1][b * H_ + j] = (f16)hreg[bb];
        if (!AUGRU) interests_out[((size_t)gb * T_ + t) * H_ + j] = (f16)hreg[bb];
      }
      __syncthreads();
      p ^= 1;
    }
  }
  if (AUGRU) {
    hout[(size_t)(b0 + bp) * H_ + j]     = hreg[0];
    hout[(size_t)(b0 + bp + 2) * H_ + j] = hreg[1];
  }
}

// ---------------------------------------------------------------- attention
__global__ __launch_bounds__(320, 2) void attn_kernel(
    const float* __restrict__ query,
    const f16* __restrict__ interests,
    const f16* __restrict__ B1h, const f16* __restrict__ C1h,
    const f16* __restrict__ W2h, const f16* __restrict__ Wfh,
    const float* __restrict__ qdotp, const float* __restrict__ b2,
    const float* __restrict__ bfp,
    float* __restrict__ logits)
{
  __shared__ alignas(16) f16 B1s[80 * 128];
  __shared__ alignas(16) f16 C1s[80 * 128];
  __shared__ alignas(16) f16 kt[TS_ * 128];
  __shared__ alignas(16) f16 qh[128];
  __shared__ alignas(16) f16 W2s[40 * 80];
  __shared__ alignas(16) f16 Wfs[48];
  __shared__ alignas(16) f16 h1t[TS_ * 80];
  __shared__ alignas(16) f16 h2t[TS_ * 40];
  __shared__ float qd[80];
  __shared__ float b2s[40];

  const int tid = threadIdx.x;
  const int b = blockIdx.x >> 2;
  const int t0 = (blockIdx.x & 3) * TS_;

  for (int i = tid; i < 80 * 128 / 8; i += 320) ((uint4*)B1s)[i] = ((const uint4*)B1h)[i];
  for (int i = tid; i < 80 * 128 / 8; i += 320) ((uint4*)C1s)[i] = ((const uint4*)C1h)[i];
  for (int i = tid; i < 40 * 80 / 8; i += 320) ((uint4*)W2s)[i] = ((const uint4*)W2h)[i];
  if (tid < 40) { Wfs[tid] = Wfh[tid]; b2s[tid] = b2[tid]; }
  if (tid < 80) qd[tid] = qdotp[b * 80 + tid];
  if (tid < 128) qh[tid] = (f16)query[b * 128 + tid];
  for (int i = tid; i < TS_ * 16; i += 320) {
    const int tt = i >> 4, c = i & 15;
    const int t = t0 + tt;
    uint4 v = make_uint4(0u, 0u, 0u, 0u);
    if (t < T_) v = ((const uint4*)(interests + ((size_t)b * T_ + t) * H_))[c];
    ((uint4*)kt)[i] = v;
  }
  __syncthreads();

  {
    const int og = tid % 20, tg = tid / 20;
    float acc[4][4];
#pragma unroll
    for (int a = 0; a < 4; ++a)
#pragma unroll
      for (int c = 0; c < 4; ++c) acc[a][c] = 0.f;
    for (int kc = 0; kc < 16; ++kc) {
      const int kcp = (kc + og) & 15;
      H8U qv; qv.v = *(const h8*)&qh[kcp * 8];
      H8U bv[4], cv[4], kv[4];
#pragma unroll
      for (int oi = 0; oi < 4; ++oi) {
        bv[oi].v = *(const h8*)&B1s[(og * 4 + oi) * 128 + kcp * 8];
        cv[oi].v = *(const h8*)&C1s[(og * 4 + oi) * 128 + kcp * 8];
      }
#pragma unroll
      for (int ti = 0; ti < 4; ++ti) kv[ti].v = *(const h8*)&kt[(tg * 4 + ti) * 128 + kcp * 8];
#pragma unroll
      for (int ti = 0; ti < 4; ++ti) {
        H8U mv;
#pragma unroll
        for (int q = 0; q < 4; ++q) mv.p[q] = qv.p[q] * kv[ti].p[q];
#pragma unroll
        for (int oi = 0; oi < 4; ++oi)
#pragma unroll
          for (int q = 0; q < 4; ++q) {
            acc[ti][oi] = dot2a(bv[oi].p[q], kv[ti].p[q], acc[ti][oi]);
            acc[ti][oi] = dot2a(cv[oi].p[q], mv.p[q],     acc[ti][oi]);
          }
      }
    }
#pragma unroll
    for (int ti = 0; ti < 4; ++ti)
#pragma unroll
      for (int oi = 0; oi < 4; ++oi) {
        const int o = og * 4 + oi, t = tg * 4 + ti;
        h1t[t * 80 + o] = (f16)sig_(acc[ti][oi] + qd[o]);
      }
  }
  __syncthreads();
  {
    const int o2g = tid % 10, tg = tid / 10;
    float acc[2][4];
#pragma unroll
    for (int a = 0; a < 2; ++a)
#pragma unroll
      for (int c = 0; c < 4; ++c) acc[a][c] = 0.f;
    for (int kc = 0; kc < 10; ++kc) {
      const int kcp = (kc + o2g) % 10;
      H8U wv[4], hv[2];
#pragma unroll
      for (int oi = 0; oi < 4; ++oi) wv[oi].v = *(const h8*)&W2s[(o2g * 4 + oi) * 80 + kcp * 8];
#pragma unroll
      for (int ti = 0; ti < 2; ++ti) hv[ti].v = *(const h8*)&h1t[(tg * 2 + ti) * 80 + kcp * 8];
#pragma unroll
      for (int ti = 0; ti < 2; ++ti)
#pragma unroll
        for (int oi = 0; oi < 4; ++oi)
#pragma unroll
          for (int q = 0; q < 4; ++q) acc[ti][oi] = dot2a(wv[oi].p[q], hv[ti].p[q], acc[ti][oi]);
    }
#pragma unroll
    for (int ti = 0; ti < 2; ++ti)
#pragma unroll
      for (int oi = 0; oi < 4; ++oi) {
        const int o = o2g * 4 + oi, t = tg * 2 + ti;
        h2t[t * 40 + o] = (f16)sig_(acc[ti][oi] + b2s[o]);
      }
  }
  __syncthreads();
  if (tid < TS_) {
    const int t = t0 + tid;
    if (t < T_) {
      float acc = 0.f;
      for (int kc = 0; kc < 5; ++kc) {
        H8U wv, hv;
        wv.v = *(const h8*)&Wfs[kc * 8];
        hv.v = *(const h8*)&h2t[tid * 40 + kc * 8];
#pragma unroll
        for (int q = 0; q < 4; ++q) acc = dot2a(wv.p[q], hv.p[q], acc);
      }
      logits[(size_t)b * T_ + t] = (acc + bfp[0]) * 0.088388347648318447f;
    }
  }
}

// ---------------------------------------------------------------- softmax
__global__ __launch_bounds__(256, 1) void softmax_kernel(
    const float* __restrict__ logits, const int* __restrict__ lens,
    float* __restrict__ scores)
{
  __shared__ float red[256];
  const int b = blockIdx.x, tid = threadIdx.x;
  const int len = lens[b];
  float v = -1e30f;
  if (tid < T_ && tid < len) v = logits[(size_t)b * T_ + tid];
  red[tid] = v; __syncthreads();
  for (int s = 128; s > 0; s >>= 1) {
    if (tid < s) red[tid] = fmaxf(red[tid], red[tid + s]);
    __syncthreads();
  }
  const float mx = red[0]; __syncthreads();
  float e = 0.f;
  if (tid < T_ && tid < len) e = __expf(v - mx);
  red[tid] = e; __syncthreads();
  for (int s = 128; s > 0; s >>= 1) {
    if (tid < s) red[tid] += red[tid + s];
    __syncthreads();
  }
  const float inv = 1.f / red[0];
  if (tid < T_) scores[(size_t)b * T_ + tid] = e * inv;
}

// ---------------------------------------------------------------- launcher
extern "C" void kernel_launch(void* const* d_in, const int* in_sizes, int n_in,
                              void* d_out, int out_size, void* d_ws, size_t ws_size,
                              hipStream_t stream)
{
  (void)in_sizes; (void)n_in; (void)out_size;
  const float* query = (const float*)d_in[0];
  const float* keys  = (const float*)d_in[1];
  const int*   lens  = (const int*)d_in[2];
  const float* Wih_e = (const float*)d_in[3];
  const float* Whh_e = (const float*)d_in[4];
  const float* bih_e = (const float*)d_in[5];
  const float* bhh_e = (const float*)d_in[6];
  const float* Wih_a = (const float*)d_in[7];
  const float* Whh_a = (const float*)d_in[8];
  const float* bih_a = (const float*)d_in[9];
  const float* bhh_a = (const float*)d_in[10];
  const float* W1 = (const float*)d_in[11];
  const float* b1 = (const float*)d_in[12];
  const float* W2 = (const float*)d_in[13];
  const float* b2 = (const float*)d_in[14];
  const float* Wf = (const float*)d_in[15];
  const float* bf = (const float*)d_in[16];

  char* w = (char*)d_ws;
  size_t off = 0;
  auto take = [&](size_t bytes) { char* p = w + off; off += (bytes + 255) & ~(size_t)255; return p; };

  // common small buffers
  f16*   interests = (f16*)take((size_t)B_ * T_ * H_ * 2);
  float* logits    = (float*)take((size_t)B_ * T_ * 4);
  float* scores    = (float*)take((size_t)B_ * T_ * 4);
  f16*   wih_e_h = (f16*)take(G3_ * H_ * 2);
  f16*   whh_e_h = (f16*)take(G3_ * H_ * 2);
  f16*   wih_a_h = (f16*)take(G3_ * H_ * 2);
  f16*   whh_a_h = (f16*)take(G3_ * H_ * 2);
  f16*   B1h = (f16*)take(80 * 128 * 2);
  f16*   C1h = (f16*)take(80 * 128 * 2);
  float* A1f = (float*)take(80 * 128 * 4);
  f16*   W2h = (f16*)take(40 * 80 * 2);
  f16*   Wfh = (f16*)take(64 * 2);
  float* qdotp = (float*)take((size_t)B_ * 80 * 4);

  const size_t small_off = off;
  // new path: full gi buffer [B*T,384] f16
  f16* gi_big = (f16*)take((size_t)B_ * T_ * G3_ * 2);
  const size_t need_big = off;
  const bool big = (ws_size >= need_big);
  // fallback path: chunked gi scratch
  off = small_off;
  f16* gi_ws = (f16*)take((size_t)SCAN_BLOCKS * CH_ * 4 * G3_ * 2);

  const int prep_tasks = 4 * G3_ * H_ + 3 * 80 * 128 + 40 * 80 + 40;
  prep_kernel<<<(prep_tasks + 255) / 256, 256, 0, stream>>>(
      Wih_e, Whh_e, Wih_a, Whh_a, W1, W2, Wf,
      wih_e_h, whh_e_h, wih_a_h, whh_a_h, B1h, C1h, A1f, W2h, Wfh);
  qdot_kernel<<<B_, 128, 0, stream>>>(query, A1f, b1, qdotp);

  if (big) {
    gi_gemm_kernel<1><<<(B_ * T_ / 128) * 2, 256, 0, stream>>>(
        keys, (const f16*)nullptr, wih_e_h, bih_e, gi_big);
    srec_kernel<0><<<B_ / 2, 256, 0, stream>>>(
        gi_big, lens, whh_e_h, bhh_e, (const float*)nullptr, interests, (float*)nullptr);
    attn_kernel<<<B_ * 4, 320, 0, stream>>>(
        query, interests, B1h, C1h, W2h, Wfh, qdotp, b2, bf, logits);
    softmax_kernel<<<B_, 256, 0, stream>>>(logits, lens, scores);
    gi_gemm_kernel<0><<<(B_ * T_ / 128) * 2, 256, 0, stream>>>(
        (const float*)nullptr, interests, wih_a_h, bih_a, gi_big);
    srec_kernel<1><<<B_ / 2, 256, 0, stream>>>(
        gi_big, lens, whh_a_h, bhh_a, scores, (f16*)nullptr, (float*)d_out);
  } else {
    scan_kernel<0><<<SCAN_BLOCKS, 256, 0, stream>>>(
        keys, (const f16*)nullptr, lens, wih_e_h, whh_e_h, bih_e, bhh_e,
        (const float*)nullptr, interests, (float*)nullptr, gi_ws);
    attn_kernel<<<B_ * 4, 320, 0, stream>>>(
        query, interests, B1h, C1h, W2h, Wfh, qdotp, b2, bf, logits);
    softmax_kernel<<<B_, 256, 0, stream>>>(logits, lens, scores);
    scan_kernel<1><<<SCAN_BLOCKS, 256, 0, stream>>>(
        (const float*)nullptr, interests, lens, wih_a_h, whh_a_h, bih_a, bhh_a,
        scores, (f16*)nullptr, (float*)d_out, gi_ws);
  }
}

// Round 4
// 1067.975 us; speedup vs baseline: 1.7872x; 1.1954x over previous
//
#include <hip/hip_runtime.h>
#include <hip/hip_fp16.h>
#include <stdint.h>

// DIEN (GRU -> DIN attention -> AUGRU) on MI355X.
// R4: attention rewritten on MFMA (16x16x32 f16), softmax fused into it.
//   - weights pre-packed into MFMA B-fragment layout by prep (wf1: [5nt][8ks][64][8],
//     wf2: [3nt][3ks][64][8], zero-padded); k staged in A-fragment layout.
//   - K=256 of phase1 = [k | q*k]: second half computed in-register (pk_mul by q frags).
//   - all MFMA operand reads are linear conflict-free ds_read_b128.
// gi_gemm / srec / prep / qdot unchanged from R3 (verified).

#define B_   1024
#define T_   200
#define H_   128
#define G3_  384
#define CH_  32
#define SCAN_BLOCKS 256

#define MT1  13   // phase1 M tiles (208 rows >= 200)
#define NT1  5    // phase1 N tiles (80 outs)
#define NT2  3    // phase2 N tiles (48 >= 40 outs)
#define KS2N 3    // phase2 K steps (96 >= 80)

typedef _Float16 f16;
typedef _Float16 h2 __attribute__((ext_vector_type(2)));
typedef _Float16 h8 __attribute__((ext_vector_type(8)));
typedef float f32x4 __attribute__((ext_vector_type(4)));

union H8U { h8 v; h2 p[4]; };

#define USE_FDOT2 1

__device__ __forceinline__ float dot2a(h2 a, h2 b, float acc) {
#if USE_FDOT2
  return __builtin_amdgcn_fdot2(a, b, acc, false);
#else
  return fmaf((float)a[1], (float)b[1], fmaf((float)a[0], (float)b[0], acc));
#endif
}

__device__ __forceinline__ f32x4 mfma_h(h8 a, h8 b, f32x4 c) {
  return __builtin_amdgcn_mfma_f32_16x16x32_f16(a, b, c, 0, 0, 0);
}

__device__ __forceinline__ float sig_(float x)  { return 1.f / (1.f + __expf(-x)); }
__device__ __forceinline__ float tanh_(float x) { return 1.f - 2.f / (__expf(2.f * x) + 1.f); }

// ---------------------------------------------------------------- prep
__global__ void prep_kernel(
    const float* __restrict__ Wih_e, const float* __restrict__ Whh_e,
    const float* __restrict__ Wih_a, const float* __restrict__ Whh_a,
    const float* __restrict__ W1, const float* __restrict__ W2,
    const float* __restrict__ Wf,
    f16* __restrict__ wih_e_h, f16* __restrict__ whh_e_h,
    f16* __restrict__ wih_a_h, f16* __restrict__ whh_a_h,
    float* __restrict__ A1f, f16* __restrict__ Wfh,
    f16* __restrict__ wf1p, f16* __restrict__ wf2p)
{
  int i = blockIdx.x * 256 + threadIdx.x;
  const int NW = G3_ * H_;
  if (i < NW) { wih_e_h[i] = (f16)Wih_e[i]; return; }  i -= NW;
  if (i < NW) { whh_e_h[i] = (f16)Whh_e[i]; return; }  i -= NW;
  if (i < NW) { wih_a_h[i] = (f16)Wih_a[i]; return; }  i -= NW;
  if (i < NW) { whh_a_h[i] = (f16)Whh_a[i]; return; }  i -= NW;
  const int NB = 80 * 128;
  if (i < NB) { int o = i >> 7, jj = i & 127;
    A1f[i] = W1[o * 512 + jj] + W1[o * 512 + 256 + jj]; return; }  i -= NB;
  if (i < 40) { Wfh[i] = (f16)Wf[i]; return; }  i -= 40;
  // wf1: phase1 B fragments. element (nt,ks,lane,ii):
  //   kk = ks*32 + (lane>>4)*8 + ii ; o = nt*16 + (lane&15)
  //   kk<128 -> B1[o][kk] = W1[o,128+kk] - W1[o,256+kk] ; else C1[o][kk-128] = W1[o,384+kk-128]
  if (i < NT1 * 8 * 64 * 8) {
    const int ii = i & 7, lane = (i >> 3) & 63, ks = (i >> 9) & 7, nt = i >> 12;
    const int kk = ks * 32 + ((lane >> 4) << 3) + ii;
    const int o = nt * 16 + (lane & 15);
    float v;
    if (kk < 128) v = W1[o * 512 + 128 + kk] - W1[o * 512 + 256 + kk];
    else          v = W1[o * 512 + 384 + (kk - 128)];
    wf1p[i] = (f16)v; return;
  }  i -= NT1 * 8 * 64 * 8;
  // wf2: phase2 B fragments (zero-padded past k=80 / o2=40)
  if (i < NT2 * KS2N * 64 * 8) {
    const int ii = i & 7, lane = (i >> 3) & 63, rem = i >> 9;
    const int ks = rem % KS2N, nt = rem / KS2N;
    const int k = ks * 32 + ((lane >> 4) << 3) + ii;
    const int o2 = nt * 16 + (lane & 15);
    wf2p[i] = (k < 80 && o2 < 40) ? (f16)W2[o2 * 80 + k] : (f16)0.f;
  }
}

// qdot[b][o] = b1[o] + sum_j A1[o][j] * q[b][j]
__global__ void qdot_kernel(const float* __restrict__ query, const float* __restrict__ A1f,
                            const float* __restrict__ b1, float* __restrict__ qdotp)
{
  const int b = blockIdx.x, o = threadIdx.x;
  if (o >= 80) return;
  float acc = b1[o];
  const float* qa = query + b * H_;
  const float* aa = A1f + o * H_;
  for (int jj = 0; jj < H_; ++jj) acc = fmaf(aa[jj], qa[jj], acc);
  qdotp[b * 80 + o] = acc;
}

// ---------------------------------------------------------------- gi GEMM (unchanged)
template <int XF32>
__global__ __launch_bounds__(256, 2) void gi_gemm_kernel(
    const float* __restrict__ xf32,
    const f16*  __restrict__ xh,
    const f16*  __restrict__ wih,
    const float* __restrict__ bih,
    f16* __restrict__ gi)
{
  __shared__ alignas(16) f16 xs[128 * H_];
  __shared__ alignas(16) f16 ws[192 * H_];
  const int tid = threadIdx.x;
  const int m0   = (blockIdx.x >> 1) * 128;
  const int half = blockIdx.x & 1;

  if (XF32) {
    for (int i = tid; i < 128 * 32; i += 256) {
      const int r = i >> 5, c = i & 31;
      float4 v = ((const float4*)(xf32 + (size_t)(m0 + r) * H_))[c];
      f16* dst = &xs[r * H_ + c * 4];
      dst[0] = (f16)v.x; dst[1] = (f16)v.y; dst[2] = (f16)v.z; dst[3] = (f16)v.w;
    }
  } else {
    const uint4* src = (const uint4*)(xh + (size_t)m0 * H_);
    for (int i = tid; i < 128 * 16; i += 256) ((uint4*)xs)[i] = src[i];
  }
  {
    const uint4* wsrc = (const uint4*)(wih + (size_t)half * 192 * H_);
    for (int i = tid; i < 192 * 16; i += 256) ((uint4*)ws)[i] = wsrc[i];
  }
  const int mg = tid >> 4;
  const int n0 = tid & 15;
  const int cb = half * 192 + n0 * 12;
  float bias[12];
#pragma unroll
  for (int ci = 0; ci < 12; ++ci) bias[ci] = bih[cb + ci];
  __syncthreads();

  float acc[8][12];
#pragma unroll
  for (int a = 0; a < 8; ++a)
#pragma unroll
    for (int c = 0; c < 12; ++c) acc[a][c] = 0.f;

  for (int kc = 0; kc < 16; ++kc) {
    const int kcp = (kc + n0) & 15;
    H8U xr[8], wr[12];
#pragma unroll
    for (int mi = 0; mi < 8; ++mi)
      xr[mi].v = *(const h8*)&xs[(mg * 8 + mi) * H_ + kcp * 8];
#pragma unroll
    for (int ci = 0; ci < 12; ++ci)
      wr[ci].v = *(const h8*)&ws[(n0 * 12 + ci) * H_ + kcp * 8];
#pragma unroll
    for (int mi = 0; mi < 8; ++mi)
#pragma unroll
      for (int ci = 0; ci < 12; ++ci)
#pragma unroll
        for (int q = 0; q < 4; ++q)
          acc[mi][ci] = dot2a(xr[mi].p[q], wr[ci].p[q], acc[mi][ci]);
  }

#pragma unroll
  for (int mi = 0; mi < 8; ++mi) {
    const size_t row = (size_t)(m0 + mg * 8 + mi);
    f16 o12[12];
#pragma unroll
    for (int ci = 0; ci < 12; ++ci) o12[ci] = (f16)(acc[mi][ci] + bias[ci]);
    f16* dst = gi + row * G3_ + cb;
#pragma unroll
    for (int s = 0; s < 3; ++s)
      ((uint2*)dst)[s] = *(const uint2*)&o12[s * 4];
  }
}

// ---------------------------------------------------------------- recurrence (unchanged)
template <int AUGRU>
__global__ __launch_bounds__(256, 2) void srec_kernel(
    const f16*  __restrict__ gi_all,
    const int*  __restrict__ lens,
    const f16*  __restrict__ whh,
    const float* __restrict__ bhh,
    const float* __restrict__ scores,
    f16*  __restrict__ interests_out,
    float* __restrict__ hout)
{
  __shared__ f16 hbuf[2][2 * H_];

  const int tid = threadIdx.x;
  const int j  = tid & 127;
  const int bp = tid >> 7;
  const int b0 = blockIdx.x * 2;
  const int gb = b0 + bp;

  hbuf[0][tid] = (f16)0.f;
  const int mylen = lens[gb];   // direct global read (no pre-barrier LDS hazard)

  const float bhr = bhh[j], bhz = bhh[j + 128], bhn = bhh[j + 256];

  H8U wr_r[16], wr_z[16], wr_n[16];
#pragma unroll
  for (int c = 0; c < 16; ++c) {
    wr_r[c].v = *(const h8*)(whh + (size_t)(j)       * H_ + c * 8);
    wr_z[c].v = *(const h8*)(whh + (size_t)(j + 128) * H_ + c * 8);
    wr_n[c].v = *(const h8*)(whh + (size_t)(j + 256) * H_ + c * 8);
  }

  const f16* gibase = gi_all + (size_t)gb * T_ * G3_;
  float h = 0.f;
  int p = 0;

  f16 a0 = gibase[j], a1 = gibase[j + 128], a2 = gibase[j + 256];
  float sc = AUGRU ? scores[(size_t)gb * T_] : 0.f;
  __syncthreads();

  for (int t = 0; t < T_; ++t) {
    const int tn = (t + 1 < T_) ? (t + 1) : t;
    const f16* gn = gibase + (size_t)tn * G3_;
    const f16 n0_ = gn[j], n1_ = gn[j + 128], n2_ = gn[j + 256];
    const float scn = AUGRU ? scores[(size_t)gb * T_ + tn] : 0.f;

    float dr = 0.f, dz = 0.f, dn = 0.f;
#pragma unroll
    for (int kc = 0; kc < 16; ++kc) {
      H8U hv;
      hv.v = *(const h8*)&hbuf[p][bp * H_ + kc * 8];
#pragma unroll
      for (int q = 0; q < 4; ++q) {
        dr = dot2a(wr_r[kc].p[q], hv.p[q], dr);
        dz = dot2a(wr_z[kc].p[q], hv.p[q], dz);
        dn = dot2a(wr_n[kc].p[q], hv.p[q], dn);
      }
    }
    const float gr  = (float)a0 + dr + bhr;
    const float gz  = (float)a1 + dz + bhz;
    const float gin = (float)a2;
    const float r  = sig_(gr);
    const float nn = tanh_(gin + r * (dn + bhn));
    float hnew;
    if (AUGRU) {
      const float u = sig_(gz) * sc;
      hnew = (1.f - u) * h + u * nn;
    } else {
      const float z = sig_(gz);
      hnew = (1.f - z) * nn + z * h;
    }
    if (t < mylen) h = hnew;
    hbuf[p ^ 1][bp * H_ + j] = (f16)h;
    if (!AUGRU) interests_out[((size_t)gb * T_ + t) * H_ + j] = (f16)h;
    a0 = n0_; a1 = n1_; a2 = n2_; sc = scn;
    __syncthreads();
    p ^= 1;
  }
  if (AUGRU) hout[(size_t)gb * H_ + j] = h;
}

// ================================================================ fallback monolithic scan
template <int AUGRU>
__global__ __launch_bounds__(256, 1) void scan_kernel(
    const float* __restrict__ keys_f32,
    const f16*  __restrict__ x_f16,
    const int*  __restrict__ lens,
    const f16*  __restrict__ wih,
    const f16*  __restrict__ whh,
    const float* __restrict__ bih,
    const float* __restrict__ bhh,
    const float* __restrict__ scores,
    f16*  __restrict__ interests_out,
    float* __restrict__ hout,
    f16*  __restrict__ gi_all)
{
  __shared__ alignas(16) f16 wlds[G3_ * H_];
  __shared__ alignas(16) f16 xlds[CH_ * 4 * H_];
  __shared__ alignas(16) f16 hbuf[2][4 * H_];
  __shared__ float bihs[G3_];

  const int tid = threadIdx.x;
  const int b0 = blockIdx.x * 4;
  f16* gi_ws = gi_all + (size_t)blockIdx.x * (CH_ * 4 * G3_);

  for (int i = tid; i < G3_; i += 256) bihs[i] = bih[i];
  for (int i = tid; i < 2 * 4 * H_; i += 256) ((f16*)hbuf)[i] = (f16)0.f;
  {
    const uint4* src = (const uint4*)wih;
    uint4* dst = (uint4*)wlds;
    for (int idx = tid; idx < G3_ * H_ / 8; idx += 256) dst[idx] = src[idx];
  }

  const int j  = tid & 127;
  const int bp = tid >> 7;
  const int len0 = lens[b0 + bp];
  const int len1 = lens[b0 + bp + 2];
  const float bhr = bhh[j], bhz = bhh[j + 128], bhn = bhh[j + 256];
  const int mg = tid >> 4;
  const int n0 = tid & 15;

  H8U wr_r[16], wr_z[16], wr_n[16];
#pragma unroll
  for (int c = 0; c < 16; ++c) {
    wr_r[c].v = *(const h8*)(whh + (size_t)(j)       * H_ + c * 8);
    wr_z[c].v = *(const h8*)(whh + (size_t)(j + 128) * H_ + c * 8);
    wr_n[c].v = *(const h8*)(whh + (size_t)(j + 256) * H_ + c * 8);
  }

  float hreg[2] = {0.f, 0.f};
  int p = 0;
  __syncthreads();

  for (int t0 = 0; t0 < T_; t0 += CH_) {
    const int S = (T_ - t0 < CH_) ? (T_ - t0) : CH_;
    if (AUGRU) {
      const int NV = S * 4 * 16;
      for (int idx = tid; idx < NV; idx += 256) {
        int b = idx / (S * 16);
        int rem = idx - b * (S * 16);
        int tp = rem >> 4, c = rem & 15;
        const uint4* src = (const uint4*)(x_f16 + ((size_t)(b0 + b) * T_ + (t0 + tp)) * H_);
        ((uint4*)xlds)[(tp * 4 + b) * 16 + c] = src[c];
      }
    } else {
      const int NV = S * 4 * 32;
      for (int idx = tid; idx < NV; idx += 256) {
        int b = idx / (S * 32);
        int rem = idx - b * (S * 32);
        int tp = rem >> 5, c = rem & 31;
        const float4* src = (const float4*)(keys_f32 + ((size_t)(b0 + b) * T_ + (t0 + tp)) * H_);
        float4 v = src[c];
        f16* dst = &xlds[(tp * 4 + b) * H_ + c * 4];
        dst[0] = (f16)v.x; dst[1] = (f16)v.y; dst[2] = (f16)v.z; dst[3] = (f16)v.w;
      }
    }
    __syncthreads();
    for (int ngrp = 0; ngrp < 3; ++ngrp) {
      float acc[8][8];
#pragma unroll
      for (int a = 0; a < 8; ++a)
#pragma unroll
        for (int c = 0; c < 8; ++c) acc[a][c] = 0.f;
      for (int kc = 0; kc < 16; ++kc) {
        const int kcp = (kc + n0) & 15;
        H8U xr[8], wr[8];
#pragma unroll
        for (int mi = 0; mi < 8; ++mi)
          xr[mi].v = *(const h8*)&xlds[(mg * 8 + mi) * H_ + kcp * 8];
#pragma unroll
        for (int ni = 0; ni < 8; ++ni)
          wr[ni].v = *(const h8*)&wlds[(n0 * 24 + ngrp * 8 + ni) * H_ + kcp * 8];
#pragma unroll
        for (int mi = 0; mi < 8; ++mi)
#pragma unroll
          for (int ni = 0; ni < 8; ++ni)
#pragma unroll
            for (int q = 0; q < 4; ++q)
              acc[mi][ni] = dot2a(xr[mi].p[q], wr[ni].p[q], acc[mi][ni]);
      }
#pragma unroll
      for (int mi = 0; mi < 8; ++mi) {
        const int pr = mg * 8 + mi;
        if (pr < S * 4) {
          H8U o8;
#pragma unroll
          for (int ni = 0; ni < 8; ++ni) {
            const int g = n0 * 24 + ngrp * 8 + ni;
            o8.p[ni >> 1][ni & 1] = (f16)(acc[mi][ni] + bihs[g]);
          }
          *(h8*)&gi_ws[(size_t)pr * G3_ + n0 * 24 + ngrp * 8] = o8.v;
        }
      }
    }
    __syncthreads();
    for (int tp = 0; tp < S; ++tp) {
      const int t = t0 + tp;
      float hr[2] = {0.f, 0.f}, hz[2] = {0.f, 0.f}, hn[2] = {0.f, 0.f};
#pragma unroll
      for (int kc = 0; kc < 16; ++kc) {
        H8U hv0, hv1;
        hv0.v = *(const h8*)&hbuf[p][(bp)     * H_ + kc * 8];
        hv1.v = *(const h8*)&hbuf[p][(bp + 2) * H_ + kc * 8];
#pragma unroll
        for (int q = 0; q < 4; ++q) {
          hr[0] = dot2a(wr_r[kc].p[q], hv0.p[q], hr[0]);
          hz[0] = dot2a(wr_z[kc].p[q], hv0.p[q], hz[0]);
          hn[0] = dot2a(wr_n[kc].p[q], hv0.p[q], hn[0]);
          hr[1] = dot2a(wr_r[kc].p[q], hv1.p[q], hr[1]);
          hz[1] = dot2a(wr_z[kc].p[q], hv1.p[q], hz[1]);
          hn[1] = dot2a(wr_n[kc].p[q], hv1.p[q], hn[1]);
        }
      }
#pragma unroll
      for (int bb = 0; bb < 2; ++bb) {
        const int b = bp + bb * 2;
        const int gb = b0 + b;
        const f16* gi = &gi_ws[(size_t)(tp * 4 + b) * G3_];
        const float gr  = (float)gi[j]       + hr[bb] + bhr;
        const float gz  = (float)gi[j + 128] + hz[bb] + bhz;
        const float gin = (float)gi[j + 256];
        const float r = sig_(gr);
        const float nn = tanh_(gin + r * (hn[bb] + bhn));
        float hnew;
        if (AUGRU) {
          const float a = scores[(size_t)gb * T_ + t];
          const float u = sig_(gz) * a;
          hnew = (1.f - u) * hreg[bb] + u * nn;
        } else {
          const float z = sig_(gz);
          hnew = (1.f - z) * nn + z * hreg[bb];
        }
        const int mylen = bb ? len1 : len0;
        if (t < mylen) hreg[bb] = hnew;
        hbuf[p ^ 1][b * H_ + j] = (f16)hreg[bb];
        if (!AUGRU) interests_out[((size_t)gb * T_ + t) * H_ + j] = (f16)hreg[bb];
      }
      __syncthreads();
      p ^= 1;
    }
  }
  if (AUGRU) {
    hout[(size_t)(b0 + bp) * H_ + j]     = hreg[0];
    hout[(size_t)(b0 + bp + 2) * H_ + j] = hreg[1];
  }
}

// ---------------------------------------------------------------- attention (MFMA, softmax fused)
// One block per batch, 512 threads = 8 waves. Tile math in the header comment.
__global__ __launch_bounds__(512, 1) void attn_kernel(
    const float* __restrict__ query,
    const f16* __restrict__ interests,
    const f16* __restrict__ wf1g,     // [5][8][64][8]
    const f16* __restrict__ wf2g,     // [3][3][64][8]
    const f16* __restrict__ wfg,      // Wf f16 [40]
    const float* __restrict__ qdotp,  // [B][80]
    const float* __restrict__ b2,
    const float* __restrict__ bfp,
    const int* __restrict__ lens,
    float* __restrict__ scores)       // [B][T]
{
  __shared__ alignas(16) f16 wf1[NT1 * 8 * 64 * 8];       // 40960 B
  __shared__ alignas(16) f16 wf2[NT2 * KS2N * 64 * 8];    //  9216 B
  __shared__ alignas(16) f16 uni[29952];                  // 59904 B: ktf | (h1f + h2s)
  __shared__ alignas(16) f16 qh[128];
  __shared__ alignas(16) f16 wfv[40];
  __shared__ float qd[80];
  __shared__ float b2s[40];
  __shared__ float red[256];

  f16* ktf = uni;                       // [13][4][64][8] = 26624 f16
  f16* h1f = uni;                       // [13][3][64][8] = 19968 f16 (after ktf dead)
  f16* h2s = uni + MT1 * KS2N * 64 * 8; // [208][48] = 9984 f16

  const int tid = threadIdx.x;
  const int b = blockIdx.x;
  const int lane = tid & 63, wid = tid >> 6;
  const int row = lane & 15, kb = lane >> 4;

  // ---- stage ----
  for (int idx = tid; idx < NT1 * 8 * 64; idx += 512)
    ((uint4*)wf1)[idx] = ((const uint4*)wf1g)[idx];
  for (int idx = tid; idx < NT2 * KS2N * 64; idx += 512)
    ((uint4*)wf2)[idx] = ((const uint4*)wf2g)[idx];
  // k fragments: element (mt,ks,l,i) = interests[b, mt*16+(l&15), ks*32+(l>>4)*8+i]
  for (int idx = tid; idx < MT1 * 4 * 64; idx += 512) {
    const int l = idx & 63, ks = (idx >> 6) & 3, mt = idx >> 8;
    const int t = mt * 16 + (l & 15);
    uint4 v = make_uint4(0u, 0u, 0u, 0u);   // zero-pad rows t>=200 (keeps NaN out)
    if (t < T_)
      v = *(const uint4*)(interests + ((size_t)b * T_ + t) * H_ + ks * 32 + ((l >> 4) << 3));
    ((uint4*)ktf)[idx] = v;
  }
  if (tid < 32) {
    float4 qv = ((const float4*)(query + (size_t)b * H_))[tid];
    f16* d = &qh[tid * 4];
    d[0] = (f16)qv.x; d[1] = (f16)qv.y; d[2] = (f16)qv.z; d[3] = (f16)qv.w;
  }
  if (tid < 80) qd[tid] = qdotp[(size_t)b * 80 + tid];
  if (tid >= 128 && tid < 168) wfv[tid - 128] = wfg[tid - 128];
  if (tid >= 192 && tid < 232) b2s[tid - 192] = b2[tid - 192];
  __syncthreads();

  // ---- phase 1: h1 = sigmoid(qdot + [k | q*k] @ wf1) ----
  const int nmt = (wid + 8 < MT1) ? 2 : 1;
  const int mts[2] = { wid, wid + 8 };

  h8 qf[4];
#pragma unroll
  for (int h = 0; h < 4; ++h) qf[h] = *(const h8*)&qh[h * 32 + kb * 8];

  h8 afr[2][4], qa[2][4];
#pragma unroll
  for (int m = 0; m < 2; ++m) if (m < nmt) {
#pragma unroll
    for (int ks = 0; ks < 4; ++ks) {
      afr[m][ks] = *(const h8*)&ktf[((mts[m] * 4 + ks) * 64 + lane) * 8];
      qa[m][ks] = afr[m][ks] * qf[ks];   // v_pk_mul_f16: (q*k) fragment
    }
  }
  __syncthreads();   // all ktf reads complete; h1f may now overwrite uni

  f32x4 acc[2][NT1];
#pragma unroll
  for (int m = 0; m < 2; ++m)
#pragma unroll
    for (int n = 0; n < NT1; ++n) acc[m][n] = (f32x4){0.f, 0.f, 0.f, 0.f};

  for (int nt = 0; nt < NT1; ++nt) {
#pragma unroll
    for (int ks = 0; ks < 8; ++ks) {
      const h8 bfr = *(const h8*)&wf1[((nt * 8 + ks) * 64 + lane) * 8];
#pragma unroll
      for (int m = 0; m < 2; ++m) if (m < nmt)
        acc[m][nt] = mfma_h(ks < 4 ? afr[m][ks] : qa[m][ks - 4], bfr, acc[m][nt]);
    }
  }

  // epilogue: h1 -> phase2 A-fragment layout. C/D: col o = nt*16+row, row t = mt*16+kb*4+r
#pragma unroll
  for (int m = 0; m < 2; ++m) if (m < nmt) {
    const int mt = mts[m];
#pragma unroll
    for (int nt = 0; nt < NT1; ++nt) {
      const int o = nt * 16 + row;
      const float qdo = qd[o];
#pragma unroll
      for (int r = 0; r < 4; ++r) {
        const float val = sig_(acc[m][nt][r] + qdo);
        const int lr = kb * 4 + r;                 // t & 15
        const int ks2 = o >> 5, kb2 = (o >> 3) & 3, i2 = o & 7;
        h1f[((mt * KS2N + ks2) * 64 + (lr | (kb2 << 4))) * 8 + i2] = (f16)val;
      }
    }
  }
  // zero K-pad (k = 80..95): ks2 == 2, lanes 32..63
  for (int idx = tid; idx < MT1 * 32 * 8; idx += 512) {
    const int mt = idx >> 8, rr = idx & 255;
    h1f[((mt * KS2N + 2) * 64 + 32 + (rr >> 3)) * 8 + (rr & 7)] = (f16)0.f;
  }
  __syncthreads();

  // ---- phase 2: h2 = sigmoid(h1 @ wf2 + b2) ----
  h8 a2[2][KS2N];
#pragma unroll
  for (int m = 0; m < 2; ++m) if (m < nmt)
#pragma unroll
    for (int ks = 0; ks < KS2N; ++ks)
      a2[m][ks] = *(const h8*)&h1f[((mts[m] * KS2N + ks) * 64 + lane) * 8];

  f32x4 acc2[2][NT2];
#pragma unroll
  for (int m = 0; m < 2; ++m)
#pragma unroll
    for (int n = 0; n < NT2; ++n) acc2[m][n] = (f32x4){0.f, 0.f, 0.f, 0.f};

#pragma unroll
  for (int nt = 0; nt < NT2; ++nt)
#pragma unroll
    for (int ks = 0; ks < KS2N; ++ks) {
      const h8 bfr = *(const h8*)&wf2[((nt * KS2N + ks) * 64 + lane) * 8];
#pragma unroll
      for (int m = 0; m < 2; ++m) if (m < nmt)
        acc2[m][nt] = mfma_h(a2[m][ks], bfr, acc2[m][nt]);
    }

#pragma unroll
  for (int m = 0; m < 2; ++m) if (m < nmt) {
#pragma unroll
    for (int nt = 0; nt < NT2; ++nt) {
      const int o2 = nt * 16 + row;
      if (o2 < 40) {
        const float bo = b2s[o2];
#pragma unroll
        for (int r = 0; r < 4; ++r) {
          const int t = mts[m] * 16 + kb * 4 + r;
          h2s[t * 48 + o2] = (f16)sig_(acc2[m][nt][r] + bo);
        }
      }
    }
  }
  __syncthreads();

  // ---- phase 3 + masked softmax ----
  float logit = 0.f;
  if (tid < T_) {
    float a = 0.f;
#pragma unroll
    for (int c = 0; c < 5; ++c) {
      H8U wv, hv;
      wv.v = *(const h8*)&wfv[c * 8];
      hv.v = *(const h8*)&h2s[tid * 48 + c * 8];
#pragma unroll
      for (int q = 0; q < 4; ++q) a = dot2a(wv.p[q], hv.p[q], a);
    }
    logit = (a + bfp[0]) * 0.088388347648318447f;
  }
  const int len = lens[b];
  if (tid < 256) red[tid] = (tid < T_ && tid < len) ? logit : -1e30f;
  __syncthreads();
  for (int s = 128; s > 0; s >>= 1) {
    if (tid < s) red[tid] = fmaxf(red[tid], red[tid + s]);
    __syncthreads();
  }
  const float mx = red[0];
  __syncthreads();
  const float e = (tid < T_ && tid < len) ? __expf(logit - mx) : 0.f;
  if (tid < 256) red[tid] = e;
  __syncthreads();
  for (int s = 128; s > 0; s >>= 1) {
    if (tid < s) red[tid] += red[tid + s];
    __syncthreads();
  }
  if (tid < T_) scores[(size_t)b * T_ + tid] = e * (1.f / red[0]);
}

// ---------------------------------------------------------------- launcher
extern "C" void kernel_launch(void* const* d_in, const int* in_sizes, int n_in,
                              void* d_out, int out_size, void* d_ws, size_t ws_size,
                              hipStream_t stream)
{
  (void)in_sizes; (void)n_in; (void)out_size;
  const float* query = (const float*)d_in[0];
  const float* keys  = (const float*)d_in[1];
  const int*   lens  = (const int*)d_in[2];
  const float* Wih_e = (const float*)d_in[3];
  const float* Whh_e = (const float*)d_in[4];
  const float* bih_e = (const float*)d_in[5];
  const float* bhh_e = (const float*)d_in[6];
  const float* Wih_a = (const float*)d_in[7];
  const float* Whh_a = (const float*)d_in[8];
  const float* bih_a = (const float*)d_in[9];
  const float* bhh_a = (const float*)d_in[10];
  const float* W1 = (const float*)d_in[11];
  const float* b1 = (const float*)d_in[12];
  const float* W2 = (const float*)d_in[13];
  const float* b2 = (const float*)d_in[14];
  const float* Wf = (const float*)d_in[15];
  const float* bf = (const float*)d_in[16];

  char* w = (char*)d_ws;
  size_t off = 0;
  auto take = [&](size_t bytes) { char* p = w + off; off += (bytes + 255) & ~(size_t)255; return p; };

  // common small buffers
  f16*   interests = (f16*)take((size_t)B_ * T_ * H_ * 2);
  float* scores    = (float*)take((size_t)B_ * T_ * 4);
  f16*   wih_e_h = (f16*)take(G3_ * H_ * 2);
  f16*   whh_e_h = (f16*)take(G3_ * H_ * 2);
  f16*   wih_a_h = (f16*)take(G3_ * H_ * 2);
  f16*   whh_a_h = (f16*)take(G3_ * H_ * 2);
  float* A1f = (float*)take(80 * 128 * 4);
  f16*   Wfh = (f16*)take(64 * 2);
  f16*   wf1p = (f16*)take(NT1 * 8 * 64 * 8 * 2);
  f16*   wf2p = (f16*)take(NT2 * KS2N * 64 * 8 * 2);
  float* qdotp = (float*)take((size_t)B_ * 80 * 4);

  const size_t small_off = off;
  f16* gi_big = (f16*)take((size_t)B_ * T_ * G3_ * 2);
  const size_t need_big = off;
  const bool big = (ws_size >= need_big);
  off = small_off;
  f16* gi_ws = (f16*)take((size_t)SCAN_BLOCKS * CH_ * 4 * G3_ * 2);

  const int prep_tasks = 4 * G3_ * H_ + 80 * 128 + 40
                       + NT1 * 8 * 64 * 8 + NT2 * KS2N * 64 * 8;
  prep_kernel<<<(prep_tasks + 255) / 256, 256, 0, stream>>>(
      Wih_e, Whh_e, Wih_a, Whh_a, W1, W2, Wf,
      wih_e_h, whh_e_h, wih_a_h, whh_a_h, A1f, Wfh, wf1p, wf2p);
  qdot_kernel<<<B_, 128, 0, stream>>>(query, A1f, b1, qdotp);

  if (big) {
    gi_gemm_kernel<1><<<(B_ * T_ / 128) * 2, 256, 0, stream>>>(
        keys, (const f16*)nullptr, wih_e_h, bih_e, gi_big);
    srec_kernel<0><<<B_ / 2, 256, 0, stream>>>(
        gi_big, lens, whh_e_h, bhh_e, (const float*)nullptr, interests, (float*)nullptr);
    attn_kernel<<<B_, 512, 0, stream>>>(
        query, interests, wf1p, wf2p, Wfh, qdotp, b2, bf, lens, scores);
    gi_gemm_kernel<0><<<(B_ * T_ / 128) * 2, 256, 0, stream>>>(
        (const float*)nullptr, interests, wih_a_h, bih_a, gi_big);
    srec_kernel<1><<<B_ / 2, 256, 0, stream>>>(
        gi_big, lens, whh_a_h, bhh_a, scores, (f16*)nullptr, (float*)d_out);
  } else {
    scan_kernel<0><<<SCAN_BLOCKS, 256, 0, stream>>>(
        keys, (const f16*)nullptr, lens, wih_e_h, whh_e_h, bih_e, bhh_e,
        (const float*)nullptr, interests, (float*)nullptr, gi_ws);
    attn_kernel<<<B_, 512, 0, stream>>>(
        query, interests, wf1p, wf2p, Wfh, qdotp, b2, bf, lens, scores);
    scan_kernel<1><<<SCAN_BLOCKS, 256, 0, stream>>>(
        (const float*)nullptr, interests, lens, wih_a_h, whh_a_h, bih_a, bhh_a,
        scores, (f16*)nullptr, (float*)d_out, gi_ws);
  }
}